// Round 10
// baseline (245.449 us; speedup 1.0000x reference)
//
#include <hip/hip_runtime.h>

// Paged attention decode, GQA: B=32, H=32, KVH=8 (G=4), D=128, pages of 16.
// R10: producer/consumer wave specialization.
//  - Block = (b, part=64 tok), 512 threads = 8 waves: waves 4..7 PRODUCE
//    (pure global_load_lds streams, probe-like, never compute), waves 0..3
//    CONSUME (ds_read + butterfly scores + online softmax + PV, never touch
//    global K/V). Decouples load issue from the dependent compute chain that
//    kept every coupled design at ~4 TB/s while the probe hit ~6.9 TB/s.
//  - Ring of 2 x (4-token) chunks in LDS: kv[2][2][4][1024] = 64 KB ->
//    2 blocks/CU = 16 waves/CU (8 producer waves/CU streaming).
//  - Sync: cumulative LDS counters (ready/cons per slot), s_sleep polling,
//    no __syncthreads in the steady loop. Counted vmcnt(8) on producers.

constexpr int Dh   = 128;
constexpr int Gq   = 4;
constexpr int KVH  = 8;
constexpr int Hq   = 32;
constexpr int Bb   = 32;
constexpr int MB   = 256;
constexpr int PAGE = 16;
constexpr float SCALE = 0.08838834764831845f;

constexpr int NPARTS      = 64;
constexpr int PART_TOKENS = 64;                  // 4 pages per part
constexpr int PG_FLOATS   = PAGE * KVH * Dh;     // 16384 floats = 64 KB
constexpr int ROW_FLOATS  = KVH * Dh;            // 1024 floats per token row
constexpr int NUNITS      = Bb * NPARTS;         // 2048
constexpr int NBLOCKS     = 512;

// per-(b,part) workspace floats: acc[32 heads][128] + m[32] + l[32]
constexpr int PART_STRIDE = Hq * Dh + 2 * Hq;    // 4160

__device__ __forceinline__ void gld16(const float* g, float* l) {
    __builtin_amdgcn_global_load_lds(
        (const __attribute__((address_space(1))) void*)g,
        (__attribute__((address_space(3))) void*)l, 16, 0, 0);
}

__global__ __launch_bounds__(512, 4)
void attn_partial(const float* __restrict__ q,
                  const float* __restrict__ kc,
                  const float* __restrict__ vc,
                  const int*   __restrict__ bt,
                  const int*   __restrict__ cl,
                  float*       __restrict__ ws)
{
    // [slot][K/V][tok-in-chunk][1024 floats]  = 64 KB
    __shared__ float kv[2][2][4][1024];
    __shared__ int flags[4];                     // ready[0],ready[1],cons[0],cons[1]
    volatile int* vf = flags;

    const int t      = threadIdx.x;              // 0..511
    const int wv     = t >> 6;                   // 0..7
    const int lane   = t & 63;
    const bool prod  = (wv >= 4);
    const int pw     = wv - 4;                   // producer: token-in-chunk 0..3
    const int lane32 = lane & 31;
    const int kvh    = (wv << 1) | (lane >> 5);  // consumer: kvh 0..7
    const int doff   = lane32 * 4;

    for (int u = blockIdx.x; u < NUNITS; u += NBLOCKS) {
        const int b    = u & (Bb - 1);           // part-major: inactive units last
        const int part = u >> 5;

        const int ctx    = cl[b];
        const int pstart = part * PART_TOKENS;
        if (pstart >= ctx) continue;             // uniform across all 8 waves
        const int n   = min(PART_TOKENS, ctx - pstart);
        const int NCH = (n + 3) >> 2;            // 4-token chunks, 1..16

        __syncthreads();
        if (t < 4) flags[t] = 0;
        __syncthreads();

        const int4 pg = *(const int4*)(bt + b * MB + (pstart >> 4));
        auto physof = [&](int pi) -> int {
            return pi == 0 ? pg.x : (pi == 1 ? pg.y : (pi == 2 ? pg.z : pg.w));
        };

        if (prod) {
            // ---------------- producer: probe-like pure load stream ----------
            auto ISSUE = [&](int c) {
                const int tok  = c * 4 + pw;     // this wave's token of chunk c
                const int phys = physof(tok >> 4);
                const size_t base = (size_t)phys * PG_FLOATS
                                  + (size_t)(tok & 15) * ROW_FLOATS + lane * 4;
                const int s = c & 1;
                float* kd = &kv[s][0][pw][0];    // wave-uniform dst; HW adds lane*16
                float* vd = &kv[s][1][pw][0];
                #pragma unroll
                for (int i = 0; i < 4; ++i) gld16(kc + base + i * 256, kd + i * 256);
                #pragma unroll
                for (int i = 0; i < 4; ++i) gld16(vc + base + i * 256, vd + i * 256);
            };

            ISSUE(0);
            for (int c = 0; c < NCH; ++c) {
                if (c + 1 < NCH) {
                    const int s1 = (c + 1) & 1;
                    if (c + 1 >= 2) {            // WAR: slot must be consumed
                        const int tgt = 4 * ((c + 1) >> 1);
                        while (vf[2 + s1] < tgt) __builtin_amdgcn_s_sleep(2);
                    }
                    ISSUE(c + 1);
                    asm volatile("s_waitcnt vmcnt(8)" ::: "memory");  // chunk c landed
                } else {
                    asm volatile("s_waitcnt vmcnt(0)" ::: "memory");
                }
                if (lane == 0) atomicAdd((int*)&flags[c & 1], 1);
            }
        } else {
            // ---------------- consumer: LDS-only compute ---------------------
            float4 qv[Gq];
            {
                const float* qbase = q + (size_t)(b * Hq + kvh * Gq) * Dh + doff;
                #pragma unroll
                for (int g = 0; g < Gq; ++g) {
                    float4 x = *(const float4*)(qbase + g * Dh);
                    qv[g] = make_float4(x.x * SCALE, x.y * SCALE,
                                        x.z * SCALE, x.w * SCALE);
                }
            }
            float4 acc[Gq];
            float  m_run[Gq], l_run[Gq];
            #pragma unroll
            for (int g = 0; g < Gq; ++g) {
                acc[g] = make_float4(0.f, 0.f, 0.f, 0.f);
                m_run[g] = -1e30f;
                l_run[g] = 0.f;
            }

            for (int c = 0; c < NCH; ++c) {
                const int s   = c & 1;
                const int tgt = 4 * ((c >> 1) + 1);
                while (vf[s] < tgt) __builtin_amdgcn_s_sleep(2);

                float4 kk[4], vv[4];
                #pragma unroll
                for (int j = 0; j < 4; ++j) {
                    kk[j] = *(const float4*)&kv[s][0][j][kvh * 128 + doff];
                    vv[j] = *(const float4*)&kv[s][1][j][kvh * 128 + doff];
                }

                const int tb = c * 4;
                float sc[4][Gq];
                #pragma unroll
                for (int j = 0; j < 4; ++j) {
                    const bool vj = (tb + j) < n;
                    #pragma unroll
                    for (int g = 0; g < Gq; ++g) {
                        float d = kk[j].x * qv[g].x + kk[j].y * qv[g].y
                                + kk[j].z * qv[g].z + kk[j].w * qv[g].w;
                        d += __shfl_xor(d, 1);
                        d += __shfl_xor(d, 2);
                        d += __shfl_xor(d, 4);
                        d += __shfl_xor(d, 8);
                        d += __shfl_xor(d, 16);  // full dot in all 32 lanes
                        sc[j][g] = vj ? d : -1e30f;
                    }
                }
                #pragma unroll
                for (int g = 0; g < Gq; ++g) {
                    const float tm = fmaxf(fmaxf(sc[0][g], sc[1][g]),
                                           fmaxf(sc[2][g], sc[3][g]));
                    const float mn    = fmaxf(m_run[g], tm);
                    const float alpha = __expf(m_run[g] - mn);
                    m_run[g] = mn;
                    const float p0 = __expf(sc[0][g] - mn);
                    const float p1 = __expf(sc[1][g] - mn);
                    const float p2 = __expf(sc[2][g] - mn);
                    const float p3 = __expf(sc[3][g] - mn);
                    l_run[g] = l_run[g] * alpha + (p0 + p1 + p2 + p3);
                    acc[g].x = fmaf(p3, vv[3].x, fmaf(p2, vv[2].x,
                               fmaf(p1, vv[1].x, fmaf(p0, vv[0].x, acc[g].x * alpha))));
                    acc[g].y = fmaf(p3, vv[3].y, fmaf(p2, vv[2].y,
                               fmaf(p1, vv[1].y, fmaf(p0, vv[0].y, acc[g].y * alpha))));
                    acc[g].z = fmaf(p3, vv[3].z, fmaf(p2, vv[2].z,
                               fmaf(p1, vv[1].z, fmaf(p0, vv[0].z, acc[g].z * alpha))));
                    acc[g].w = fmaf(p3, vv[3].w, fmaf(p2, vv[2].w,
                               fmaf(p1, vv[1].w, fmaf(p0, vv[0].w, acc[g].w * alpha))));
                }

                asm volatile("" ::: "memory");   // keep signal after the reads
                if (lane == 0) atomicAdd((int*)&flags[2 + s], 1);
            }

            // write partials: head (kvh,g), dims [doff, doff+4)
            float* wp = ws + (size_t)(b * NPARTS + part) * PART_STRIDE;
            #pragma unroll
            for (int g = 0; g < Gq; ++g)
                *(float4*)(wp + (kvh * Gq + g) * Dh + doff) = acc[g];
            if (lane32 == 0) {
                #pragma unroll
                for (int g = 0; g < Gq; ++g) {
                    wp[Hq * Dh + kvh * Gq + g]      = m_run[g];
                    wp[Hq * Dh + Hq + kvh * Gq + g] = l_run[g];
                }
            }
        }
    }
}

__global__ __launch_bounds__(256, 4)
void attn_reduce(const float* __restrict__ ws,
                 const int*   __restrict__ cl,
                 float*       __restrict__ out)
{
    const int b       = blockIdx.x >> 2;
    const int quarter = blockIdx.x & 3;
    const int tid     = threadIdx.x;
    const int h       = quarter * 8 + (tid >> 5);
    const int doff    = (tid & 31) * 4;

    const int ctx = cl[b];
    const int np  = min(NPARTS, (ctx + PART_TOKENS - 1) / PART_TOKENS);

    const float* base = ws + (size_t)b * NPARTS * PART_STRIDE;

    float m = -1e30f;
    for (int p = 0; p < np; ++p)
        m = fmaxf(m, base[p * PART_STRIDE + Hq * Dh + h]);

    float L = 0.f;
    float ax = 0.f, ay = 0.f, az = 0.f, aw = 0.f;
    for (int p = 0; p < np; ++p) {
        const float* bp = base + p * PART_STRIDE;
        const float c = __expf(bp[Hq * Dh + h] - m);
        L += bp[Hq * Dh + Hq + h] * c;
        const float4 v = *(const float4*)(bp + h * Dh + doff);
        ax = fmaf(c, v.x, ax);
        ay = fmaf(c, v.y, ay);
        az = fmaf(c, v.z, az);
        aw = fmaf(c, v.w, aw);
    }
    const float inv = 1.f / L;
    float* op = out + (size_t)(b * Hq + h) * Dh + doff;
    *(float4*)op = make_float4(ax * inv, ay * inv, az * inv, aw * inv);
}

extern "C" void kernel_launch(void* const* d_in, const int* in_sizes, int n_in,
                              void* d_out, int out_size, void* d_ws, size_t ws_size,
                              hipStream_t stream) {
    const float* q  = (const float*)d_in[0];
    const float* kc = (const float*)d_in[1];
    const float* vc = (const float*)d_in[2];
    const int*   bt = (const int*)d_in[3];
    const int*   cl = (const int*)d_in[4];
    float* out = (float*)d_out;
    float* ws  = (float*)d_ws;

    attn_partial<<<dim3(NBLOCKS), dim3(512), 0, stream>>>(q, kc, vc, bt, cl, ws);
    attn_reduce<<<dim3(Bb * 4), dim3(256), 0, stream>>>(ws, cl, out);
}

// Round 11
// 226.153 us; speedup vs baseline: 1.0853x; 1.0853x over previous
//
#include <hip/hip_runtime.h>

// Paged attention decode, GQA: B=32, H=32, KVH=8 (G=4), D=128, pages of 16.
// R11: PHYSICAL-ORDER traversal experiment.
//  - build_inv inverts block_tables: inv[phys] = (b<<8)|lp, or -1 if inactive.
//  - attn_partial walks physical pages in ascending address order (dynamic
//    FIFO queue over units of 2 consecutive physical pages) -> the aggregate
//    HBM read stream is a forward-moving, ~50%-dense linear scan, vs the
//    random 64KB-granule order of all previous rounds (all capped ~4 TB/s).
//  - Per page: R7's proven structure (256 threads span the 4KB token row,
//    4-token chunks, rolled register ping-pong, shfl_xor butterfly scores,
//    online softmax, in-lane PV). Partials are per-page (part = one 16-token
//    logical page). Reduce = single-pass online-softmax merge over <=256 parts.

constexpr int Dh   = 128;
constexpr int Gq   = 4;
constexpr int KVH  = 8;
constexpr int Hq   = 32;
constexpr int Bb   = 32;
constexpr int MB   = 256;
constexpr int PAGE = 16;
constexpr float SCALE = 0.08838834764831845f;

constexpr int PG_FLOATS  = PAGE * KVH * Dh;      // 16384 floats = 64 KB
constexpr int ROW_FLOATS = KVH * Dh;             // 1024 floats per token row
constexpr int NPAGES     = Bb * MB;              // 8192 physical pages
constexpr int NUNITS     = NPAGES / 2;           // 4096 units of 2 pages

// per-(b, logical-page) workspace floats: acc[32][128] + m[32] + l[32]
constexpr int PART_STRIDE = Hq * Dh + 2 * Hq;    // 4160  (136 MB total)

constexpr size_t INV_BYTE_OFF = (size_t)192 << 20;
constexpr size_t CTR_BYTE_OFF = (size_t)200 << 20;

struct QuadR { float4 k[4], v[4]; };

__global__ void init_ctr(int* ctr) { *ctr = 0; }

__global__ __launch_bounds__(256)
void build_inv(const int* __restrict__ bt, const int* __restrict__ cl,
               int* __restrict__ inv)
{
    const int b  = blockIdx.x;                   // 0..31
    const int lp = threadIdx.x;                  // 0..255
    const int phys = bt[b * MB + lp];
    inv[phys] = (lp * PAGE < cl[b]) ? ((b << 8) | lp) : -1;
}

__global__ __launch_bounds__(256, 3)
void attn_partial(const float* __restrict__ q,
                  const float* __restrict__ kc,
                  const float* __restrict__ vc,
                  const int*   __restrict__ cl,
                  const int*   __restrict__ inv,
                  float*       __restrict__ ws,
                  int*         __restrict__ ctr)
{
    const int t      = threadIdx.x;              // 0..255
    const int kvh    = t >> 5;
    const int lane32 = t & 31;
    const int doff   = lane32 * 4;
    const int t4     = t * 4;

    __shared__ int s_unit;

    for (;;) {
        if (t == 0) s_unit = atomicAdd(ctr, 1);
        __syncthreads();
        const int unit = s_unit;
        __syncthreads();
        if (unit >= NUNITS) break;

        #pragma unroll 1
        for (int pp = 0; pp < 2; ++pp) {
            const int phys = unit * 2 + pp;      // ascending physical order
            const int code = inv[phys];
            if (code < 0) continue;
            const int b  = code >> 8;
            const int lp = code & 255;
            const int n  = min(PAGE, cl[b] - lp * PAGE);   // 1..16
            const int TC = (n + 3) >> 2;                   // 1..4 chunks

            // Q fragments, pre-scaled: head (kvh,g), dims [doff, doff+4)
            float4 qv[Gq];
            {
                const float* qbase = q + (size_t)(b * Hq + kvh * Gq) * Dh + doff;
                #pragma unroll
                for (int g = 0; g < Gq; ++g) {
                    float4 x = *(const float4*)(qbase + g * Dh);
                    qv[g] = make_float4(x.x * SCALE, x.y * SCALE,
                                        x.z * SCALE, x.w * SCALE);
                }
            }

            float4 acc[Gq];
            float  m_run[Gq], l_run[Gq];
            #pragma unroll
            for (int g = 0; g < Gq; ++g) {
                acc[g] = make_float4(0.f, 0.f, 0.f, 0.f);
                m_run[g] = -1e30f;
                l_run[g] = 0.f;
            }

            const size_t pbase = (size_t)phys * PG_FLOATS + t4;

            auto LOADQ = [&](QuadR& H, int c) {
                const float* kp = kc + pbase + (size_t)(c * 4) * ROW_FLOATS;
                const float* vp = vc + pbase + (size_t)(c * 4) * ROW_FLOATS;
                #pragma unroll
                for (int j = 0; j < 4; ++j) {
                    H.k[j] = *(const float4*)(kp + j * ROW_FLOATS);
                    H.v[j] = *(const float4*)(vp + j * ROW_FLOATS);
                }
            };

            auto COMPUTEQ = [&](const QuadR& H, int c) {
                const int tb = c * 4;
                float s[4][Gq];
                #pragma unroll
                for (int j = 0; j < 4; ++j) {
                    const bool vj = (tb + j) < n;
                    #pragma unroll
                    for (int g = 0; g < Gq; ++g) {
                        float d = H.k[j].x * qv[g].x + H.k[j].y * qv[g].y
                                + H.k[j].z * qv[g].z + H.k[j].w * qv[g].w;
                        d += __shfl_xor(d, 1);
                        d += __shfl_xor(d, 2);
                        d += __shfl_xor(d, 4);
                        d += __shfl_xor(d, 8);
                        d += __shfl_xor(d, 16);  // full dot in all 32 lanes
                        s[j][g] = vj ? d : -1e30f;
                    }
                }
                #pragma unroll
                for (int g = 0; g < Gq; ++g) {
                    const float tm = fmaxf(fmaxf(s[0][g], s[1][g]),
                                           fmaxf(s[2][g], s[3][g]));
                    const float mn    = fmaxf(m_run[g], tm);
                    const float alpha = __expf(m_run[g] - mn);
                    m_run[g] = mn;
                    const float p0 = __expf(s[0][g] - mn);
                    const float p1 = __expf(s[1][g] - mn);
                    const float p2 = __expf(s[2][g] - mn);
                    const float p3 = __expf(s[3][g] - mn);
                    l_run[g] = l_run[g] * alpha + (p0 + p1 + p2 + p3);
                    acc[g].x = fmaf(p3, H.v[3].x, fmaf(p2, H.v[2].x,
                               fmaf(p1, H.v[1].x, fmaf(p0, H.v[0].x, acc[g].x * alpha))));
                    acc[g].y = fmaf(p3, H.v[3].y, fmaf(p2, H.v[2].y,
                               fmaf(p1, H.v[1].y, fmaf(p0, H.v[0].y, acc[g].y * alpha))));
                    acc[g].z = fmaf(p3, H.v[3].z, fmaf(p2, H.v[2].z,
                               fmaf(p1, H.v[1].z, fmaf(p0, H.v[0].z, acc[g].z * alpha))));
                    acc[g].w = fmaf(p3, H.v[3].w, fmaf(p2, H.v[2].w,
                               fmaf(p1, H.v[1].w, fmaf(p0, H.v[0].w, acc[g].w * alpha))));
                }
            };

            QuadR A, B;
            LOADQ(A, 0);
            int c = 0;
            while (true) {
                if (c + 1 < TC) LOADQ(B, c + 1);
                COMPUTEQ(A, c);
                ++c; if (c >= TC) break;
                if (c + 1 < TC) LOADQ(A, c + 1);
                COMPUTEQ(B, c);
                ++c; if (c >= TC) break;
            }

            // write per-page partials: head (kvh,g), dims [doff, doff+4)
            float* wp = ws + (size_t)(b * MB + lp) * PART_STRIDE;
            #pragma unroll
            for (int g = 0; g < Gq; ++g)
                *(float4*)(wp + (kvh * Gq + g) * Dh + doff) = acc[g];
            if (lane32 == 0) {
                #pragma unroll
                for (int g = 0; g < Gq; ++g) {
                    wp[Hq * Dh + kvh * Gq + g]      = m_run[g];
                    wp[Hq * Dh + Hq + kvh * Gq + g] = l_run[g];
                }
            }
        }
    }
}

__global__ __launch_bounds__(256, 4)
void attn_reduce(const float* __restrict__ ws,
                 const int*   __restrict__ cl,
                 float*       __restrict__ out)
{
    const int b       = blockIdx.x >> 2;
    const int quarter = blockIdx.x & 3;
    const int tid     = threadIdx.x;
    const int h       = quarter * 8 + (tid >> 5);
    const int doff    = (tid & 31) * 4;

    const int ctx = cl[b];
    const int np  = (ctx + PAGE - 1) >> 4;       // 1..256 active pages

    const float* base = ws + (size_t)b * MB * PART_STRIDE;

    // single-pass online-softmax merge over parts
    float M = -1e30f, L = 0.f;
    float ax = 0.f, ay = 0.f, az = 0.f, aw = 0.f;
    for (int p = 0; p < np; ++p) {
        const float* bp = base + (size_t)p * PART_STRIDE;
        const float mp = bp[Hq * Dh + h];
        const float lp = bp[Hq * Dh + Hq + h];
        const float4 a = *(const float4*)(bp + h * Dh + doff);
        const float Mn = fmaxf(M, mp);
        const float e0 = __expf(M - Mn);
        const float e1 = __expf(mp - Mn);
        L  = L  * e0 + lp  * e1;
        ax = ax * e0 + a.x * e1;
        ay = ay * e0 + a.y * e1;
        az = az * e0 + a.z * e1;
        aw = aw * e0 + a.w * e1;
        M = Mn;
    }
    const float inv = 1.f / L;
    float* op = out + (size_t)(b * Hq + h) * Dh + doff;
    *(float4*)op = make_float4(ax * inv, ay * inv, az * inv, aw * inv);
}

extern "C" void kernel_launch(void* const* d_in, const int* in_sizes, int n_in,
                              void* d_out, int out_size, void* d_ws, size_t ws_size,
                              hipStream_t stream) {
    const float* q  = (const float*)d_in[0];
    const float* kc = (const float*)d_in[1];
    const float* vc = (const float*)d_in[2];
    const int*   bt = (const int*)d_in[3];
    const int*   cl = (const int*)d_in[4];
    float* out = (float*)d_out;
    float* ws  = (float*)d_ws;
    int*   inv = (int*)((char*)d_ws + INV_BYTE_OFF);
    int*   ctr = (int*)((char*)d_ws + CTR_BYTE_OFF);

    init_ctr<<<dim3(1), dim3(1), 0, stream>>>(ctr);
    build_inv<<<dim3(Bb), dim3(MB), 0, stream>>>(bt, cl, inv);
    attn_partial<<<dim3(768), dim3(256), 0, stream>>>(q, kc, vc, cl, inv, ws, ctr);
    attn_reduce<<<dim3(Bb * 4), dim3(256), 0, stream>>>(ws, cl, out);
}